// Round 15
// baseline (297.377 us; speedup 1.0000x reference)
//
#include <hip/hip_runtime.h>
#include <hip/hip_bf16.h>
#include <math.h>

// B=2, N=2048, M=1024, H=16, DK=64. fp32 in/out.
// R15 = R14 + two attn latency cuts:
//  (1) mask register double-buffer: tile t+1's 16 mask loads issued right
//      after barrier(t), consumed next iter (~1650 cyc cover vs ~200 before;
//      mask is L3-resident ~450-600 cyc latency).
//  (2) log2(e) folded into Wq/bq scale -> p = exp2(s*mask) via v_exp_f32
//      directly (kills the 16 v_mul/iter hidden inside __expf).
// Precision plan (absmax 9.77e-4, stable since R7):
//   all projections 1-term | QK 2-term (ql = fp32-accumulator residue) | PV 1t

typedef __attribute__((ext_vector_type(8))) short bf16x8;
typedef __attribute__((ext_vector_type(4))) float f32x4;

typedef __attribute__((address_space(1))) void gvoid;   // global
typedef __attribute__((address_space(3))) void lvoid;   // LDS

#define QSC 0.18033688011112042f   // 0.125 * log2(e): attn scale + exp2 fold

#if defined(__has_builtin)
#if __has_builtin(__builtin_amdgcn_exp2f)
#define EXP2F(x) __builtin_amdgcn_exp2f(x)
#else
#define EXP2F(x) exp2f(x)
#endif
#else
#define EXP2F(x) exp2f(x)
#endif

// async 16B/lane global->LDS copy: 64 lanes -> 1KB at wave-uniform lds base
__device__ __forceinline__ void gll16(const void* g, void* l) {
    __builtin_amdgcn_global_load_lds(
        (gvoid*)(unsigned long long)g,
        (lvoid*)(unsigned int)(unsigned long long)l,   // low 32b = LDS offset
        16, 0, 0);
}

__device__ __forceinline__ short f2b(float f) {
    union { __hip_bfloat16 h; short s; } u;
    u.h = __float2bfloat16(f);   // RNE
    return u.s;
}
__device__ __forceinline__ float b2f(short s) {
    union { short s; __hip_bfloat16 h; } u;
    u.s = s;
    return __bfloat162float(u.h);
}

// XOR-swizzled element offset inside a [rows][64]-bf16 tile (16B blocks).
__device__ __forceinline__ int sw8(int r, int k8) {       // k8 = octet 0..7
    return (r << 6) + ((k8 ^ (r & 7)) << 3);
}
__device__ __forceinline__ int swe(int r, int k) {        // element-level
    return (r << 6) + (((k >> 3) ^ (r & 7)) << 3) + (k & 7);
}

// workspace layout (SHORT offsets). Every plane = 4194304 shorts (8 MB).
#define PLANE   4194304UL
#define OFF_WH  (0UL * PLANE)    // [4][1024][1024] W hi; Wq pre-scaled by QSC
#define OFF_XH  (1UL * PLANE)    // [4096][1024] x hi
#define OFF_QH  (2UL * PLANE)    // [B,H,N,DK]
#define OFF_QL  (3UL * PLANE)
#define OFF_KH  (4UL * PLANE)    // hi only
#define OFF_VTH (5UL * PLANE)    // [B,H,DK,N] hi only
#define OFF_CH  (6UL * PLANE)    // [B,N,M] concat hi only

// ---------------------------------------------------------------------------
// Pre-split: W -> hi (Wq scaled by QSC); x -> hi only.
// ---------------------------------------------------------------------------
__global__ __launch_bounds__(256) void split_wx(
    const float* __restrict__ Wq, const float* __restrict__ Wk,
    const float* __restrict__ Wv, const float* __restrict__ Wo,
    const float* __restrict__ x,
    unsigned short* __restrict__ wh, unsigned short* __restrict__ xh)
{
    const int i = blockIdx.x * 256 + threadIdx.x;   // float4 idx, 2097152 total
    if (i < 1048576) {                               // weights
        const float* src = (i < 262144) ? Wq : (i < 524288) ? Wk
                         : (i < 786432) ? Wv : Wo;
        const float sc = (i < 262144) ? QSC : 1.0f;  // fold scale + log2e
        const int local = i & 262143;
        float4 v = ((const float4*)src)[local];
        short4 h;
        h.x = f2b(v.x * sc); h.y = f2b(v.y * sc);
        h.z = f2b(v.z * sc); h.w = f2b(v.w * sc);
        ((short4*)(wh + (size_t)(i >> 18) * 1048576))[local] = h;
    } else {                                         // x: hi only
        const int local = i - 1048576;
        float4 v = ((const float4*)x)[local];
        short4 h;
        h.x = f2b(v.x); h.y = f2b(v.y); h.z = f2b(v.z); h.w = f2b(v.w);
        ((short4*)xh)[local] = h;
    }
}

// ---------------------------------------------------------------------------
// Unified 1-term QKV GEMM: ONE launch (8,32,3) = 768 blocks, LDS 32KB.
// z=0: Q -> hi/lo planes (lo = fp32-accumulator residue); z=1: K; z=2: V^T.
// ---------------------------------------------------------------------------
__global__ __launch_bounds__(256, 4) void gemm_qkv(
    unsigned short* __restrict__ wsS,
    const float* __restrict__ bq, const float* __restrict__ bk,
    const float* __restrict__ bv)
{
    __shared__ unsigned short Ash[128 * 64];
    __shared__ unsigned short Bsh[128 * 64];

    const int mode = blockIdx.z;                     // 0 Q, 1 K, 2 V
    const unsigned short* Ah = wsS + OFF_XH;
    const unsigned short* Wh = wsS + OFF_WH + (size_t)mode * 1048576;

    const int tid  = threadIdx.x;
    const int lane = tid & 63;
    const int lm   = lane & 15;
    const int quad = lane >> 4;
    const int w    = tid >> 6;
    const int wr   = w >> 1, wc = w & 1;

    const int row0 = blockIdx.y * 128;
    const int col0 = blockIdx.x * 128;

    const int srow = lane >> 3;
    const int soct = (lane & 7) ^ (srow & 7);

    f32x4 acc[4][4] = {};

    for (int k0 = 0; k0 < 1024; k0 += 64) {
        if (k0) __syncthreads();
        #pragma unroll
        for (int i = 0; i < 4; ++i) {
            const int rb = w * 32 + i * 8;           // wave-uniform row base
            gll16(&Ah[(size_t)(row0 + rb + srow) * 1024 + k0 + soct * 8],
                  &Ash[rb * 64]);
            gll16(&Wh[(size_t)(col0 + rb + srow) * 1024 + k0 + soct * 8],
                  &Bsh[rb * 64]);
        }
        __syncthreads();
        #pragma unroll
        for (int ks = 0; ks < 2; ++ks) {
            bf16x8 afh[4], bfh[4];
            #pragma unroll
            for (int mi = 0; mi < 4; ++mi)
                afh[mi] = *(const bf16x8*)&Ash[sw8(wr * 64 + mi * 16 + lm, ks * 4 + quad)];
            #pragma unroll
            for (int ni = 0; ni < 4; ++ni)
                bfh[ni] = *(const bf16x8*)&Bsh[sw8(wc * 64 + ni * 16 + lm, ks * 4 + quad)];
            #pragma unroll
            for (int mi = 0; mi < 4; ++mi) {
                #pragma unroll
                for (int ni = 0; ni < 4; ++ni)
                    acc[mi][ni] = __builtin_amdgcn_mfma_f32_16x16x32_bf16(
                        afh[mi], bfh[ni], acc[mi][ni], 0, 0, 0);
            }
        }
    }

    unsigned short* qh  = wsS + OFF_QH;
    unsigned short* ql  = wsS + OFF_QL;
    unsigned short* kh  = wsS + OFF_KH;
    unsigned short* vth = wsS + OFF_VTH;
    const float* bias = (mode == 0) ? bq : (mode == 1) ? bk : bv;
    const float bscale = (mode == 0) ? QSC : 1.0f;

    #pragma unroll
    for (int ni = 0; ni < 4; ++ni) {
        const int f = col0 + wc * 64 + ni * 16 + lm;
        const float bvv = bias[f] * bscale;
        const int h = f >> 6, d = f & 63;
        #pragma unroll
        for (int mi = 0; mi < 4; ++mi) {
            #pragma unroll
            for (int j = 0; j < 4; ++j) {
                const int row = row0 + wr * 64 + mi * 16 + quad * 4 + j;
                const float val = acc[mi][ni][j] + bvv;
                const int bb = row >> 11, n = row & 2047;
                const short hs = f2b(val);
                if (mode == 0) {
                    const size_t idx = ((size_t)(bb * 16 + h) * 2048 + n) * 64 + d;
                    qh[idx] = hs;
                    ql[idx] = f2b(val - b2f(hs));   // fp32-accumulator residue
                } else if (mode == 1) {
                    kh[((size_t)(bb * 16 + h) * 2048 + n) * 64 + d] = hs;
                } else {
                    vth[((size_t)(bb * 16 + h) * 64 + d) * 2048 + n] = hs;
                }
            }
        }
    }
}

// ---------------------------------------------------------------------------
// 1-term output projection, 512 threads / 8 waves (R14).
// ---------------------------------------------------------------------------
__global__ __launch_bounds__(512, 2) void gemm_out(
    const unsigned short* __restrict__ Ah,
    unsigned short* __restrict__ wsS,
    const float* __restrict__ bias_p, float* __restrict__ oout)
{
    __shared__ unsigned short Ash[128 * 64];
    __shared__ unsigned short Bsh[128 * 64];

    const unsigned short* Wh = wsS + OFF_WH + 3UL * 1048576;

    const int tid  = threadIdx.x;
    const int lane = tid & 63;
    const int lm   = lane & 15;
    const int quad = lane >> 4;
    const int w    = tid >> 6;          // 0..7
    const int wr   = w >> 2;            // 0..1  (64-row half)
    const int wc   = w & 3;             // 0..3  (32-col quarter)

    const int row0 = blockIdx.y * 128;
    const int col0 = blockIdx.x * 128;

    const int srow = lane >> 3;
    const int soct = (lane & 7) ^ (srow & 7);

    f32x4 acc[4][2] = {};

    for (int k0 = 0; k0 < 1024; k0 += 64) {
        if (k0) __syncthreads();
        #pragma unroll
        for (int i = 0; i < 2; ++i) {
            const int rb = w * 16 + i * 8;
            gll16(&Ah[(size_t)(row0 + rb + srow) * 1024 + k0 + soct * 8],
                  &Ash[rb * 64]);
            gll16(&Wh[(size_t)(col0 + rb + srow) * 1024 + k0 + soct * 8],
                  &Bsh[rb * 64]);
        }
        __syncthreads();
        #pragma unroll
        for (int ks = 0; ks < 2; ++ks) {
            bf16x8 afh[4], bfh[2];
            #pragma unroll
            for (int mi = 0; mi < 4; ++mi)
                afh[mi] = *(const bf16x8*)&Ash[sw8(wr * 64 + mi * 16 + lm, ks * 4 + quad)];
            #pragma unroll
            for (int ni = 0; ni < 2; ++ni)
                bfh[ni] = *(const bf16x8*)&Bsh[sw8(wc * 32 + ni * 16 + lm, ks * 4 + quad)];
            #pragma unroll
            for (int mi = 0; mi < 4; ++mi) {
                #pragma unroll
                for (int ni = 0; ni < 2; ++ni)
                    acc[mi][ni] = __builtin_amdgcn_mfma_f32_16x16x32_bf16(
                        afh[mi], bfh[ni], acc[mi][ni], 0, 0, 0);
            }
        }
    }

    #pragma unroll
    for (int ni = 0; ni < 2; ++ni) {
        const int f = col0 + wc * 32 + ni * 16 + lm;
        const float bvv = bias_p[f];
        #pragma unroll
        for (int mi = 0; mi < 4; ++mi) {
            #pragma unroll
            for (int j = 0; j < 4; ++j) {
                const int row = row0 + wr * 64 + mi * 16 + quad * 4 + j;
                oout[(size_t)row * 1024 + f] = acc[mi][ni][j] + bvv;
            }
        }
    }
}

// ---------------------------------------------------------------------------
// Flash attention: 64 q-rows/block, deferred softmax, async K/V dbuf,
// one barrier per K-tile, MASK REGISTER DOUBLE-BUFFER (tile t+1 issued at t),
// p = exp2(s*mask) with log2e pre-folded into q. QK 2-term, PV 1-term.
// LDS 40KB -> 4 blocks/CU.
// ---------------------------------------------------------------------------
__global__ __launch_bounds__(256, 4) void attn_fast(
    const unsigned short* __restrict__ wsS, const float* __restrict__ mask,
    unsigned short* __restrict__ ch)
{
    __shared__ unsigned short Ksh[2][64 * 64];   // [buf][kcol][d] hi
    __shared__ unsigned short Vth[2][64 * 64];   // [buf][d][k]    hi
    __shared__ unsigned short Psh[4][16 * 64];   // per-wave [q][k] hi

    const int tid  = threadIdx.x;
    const int lane = tid & 63;
    const int lm   = lane & 15;
    const int quad = lane >> 4;
    const int w    = tid >> 6;

    const int q0 = blockIdx.x * 64;
    const int h  = blockIdx.y;
    const int b  = blockIdx.z;
    const int bh = b * 16 + h;

    const unsigned short* Qhg = wsS + OFF_QH  + (size_t)bh * 2048 * 64;
    const unsigned short* Qlg = wsS + OFF_QL  + (size_t)bh * 2048 * 64;
    const unsigned short* Khg = wsS + OFF_KH  + (size_t)bh * 2048 * 64;
    const unsigned short* Vhg = wsS + OFF_VTH + (size_t)bh * 64 * 2048;
    const float* Mg = mask + (size_t)b * 2048 * 2048;

    // Q frags in registers (this wave's 16 q-rows); QSC pre-folded in q
    bf16x8 qfh[2], qfl[2];
    #pragma unroll
    for (int ks = 0; ks < 2; ++ks) {
        const size_t qo = (size_t)(q0 + w * 16 + lm) * 64 + ks * 32 + quad * 8;
        qfh[ks] = *(const bf16x8*)&Qhg[qo];
        qfl[ks] = *(const bf16x8*)&Qlg[qo];
    }

    const int srow = lane >> 3;
    const int soct = (lane & 7) ^ (srow & 7);

    const int qwbase = q0 + w * 16 + quad * 4;
    const float* mrow0 = Mg + (size_t)(qwbase + 0) * 2048 + lm;
    const float* mrow1 = Mg + (size_t)(qwbase + 1) * 2048 + lm;
    const float* mrow2 = Mg + (size_t)(qwbase + 2) * 2048 + lm;
    const float* mrow3 = Mg + (size_t)(qwbase + 3) * 2048 + lm;

    // prologue: async-load tile 0 into buf 0; mask tile 0 into mbuf[0]
    #pragma unroll
    for (int i = 0; i < 2; ++i) {
        const int rb = w * 16 + i * 8;               // wave-uniform row base
        gll16(&Khg[(size_t)(rb + srow) * 64 + soct * 8],   &Ksh[0][rb * 64]);
        gll16(&Vhg[(size_t)(rb + srow) * 2048 + soct * 8], &Vth[0][rb * 64]);
    }
    float mbuf[2][4][4];
    #pragma unroll
    for (int ni = 0; ni < 4; ++ni) {
        mbuf[0][0][ni] = mrow0[ni * 16];
        mbuf[0][1][ni] = mrow1[ni * 16];
        mbuf[0][2][ni] = mrow2[ni * 16];
        mbuf[0][3][ni] = mrow3[ni * 16];
    }

    f32x4 o[4] = {};
    float lsum[4] = {0.f, 0.f, 0.f, 0.f};

    #pragma unroll 2
    for (int t = 0; t < 32; ++t) {
        const int k0 = t * 64;
        const int p  = t & 1;

        __syncthreads();   // drains vmcnt -> tile t (K/V LDS + mask regs) ready

        // async-issue tile t+1 K/V into buf 1-p, mask into mbuf[1-p]
        if (t < 31) {
            #pragma unroll
            for (int i = 0; i < 2; ++i) {
                const int rb = w * 16 + i * 8;
                gll16(&Khg[(size_t)(k0 + 64 + rb + srow) * 64 + soct * 8],
                      &Ksh[1 - p][rb * 64]);
                gll16(&Vhg[(size_t)(rb + srow) * 2048 + k0 + 64 + soct * 8],
                      &Vth[1 - p][rb * 64]);
            }
            #pragma unroll
            for (int ni = 0; ni < 4; ++ni) {
                mbuf[1 - p][0][ni] = mrow0[k0 + 64 + ni * 16];
                mbuf[1 - p][1][ni] = mrow1[k0 + 64 + ni * 16];
                mbuf[1 - p][2][ni] = mrow2[k0 + 64 + ni * 16];
                mbuf[1 - p][3][ni] = mrow3[k0 + 64 + ni * 16];
            }
        }

        // S ~= (qh+ql) K_hi^T : 2 MFMA per (ks,ni); scale+log2e in q
        f32x4 s[4] = {};
        #pragma unroll
        for (int ks = 0; ks < 2; ++ks) {
            #pragma unroll
            for (int ni = 0; ni < 4; ++ni) {
                bf16x8 kh = *(const bf16x8*)&Ksh[p][sw8(ni * 16 + lm, ks * 4 + quad)];
                s[ni] = __builtin_amdgcn_mfma_f32_16x16x32_bf16(qfh[ks], kh, s[ni], 0, 0, 0);
                s[ni] = __builtin_amdgcn_mfma_f32_16x16x32_bf16(qfl[ks], kh, s[ni], 0, 0, 0);
            }
        }

        // p = exp2(s * mask); per-lane partial row-sums; P(hi) -> own-wave LDS
        #pragma unroll
        for (int j = 0; j < 4; ++j) {
            #pragma unroll
            for (int ni = 0; ni < 4; ++ni) {
                const float pv = EXP2F(s[ni][j] * mbuf[p][j][ni]);
                lsum[j] += pv;
                Psh[w][swe(quad * 4 + j, ni * 16 + lm)] = f2b(pv);
            }
        }

        // O += P_hi @ V_hi : 1 MFMA per (ks,ni)
        #pragma unroll
        for (int ks = 0; ks < 2; ++ks) {
            bf16x8 ph = *(const bf16x8*)&Psh[w][sw8(lm, ks * 4 + quad)];
            #pragma unroll
            for (int ni = 0; ni < 4; ++ni) {
                bf16x8 vh = *(const bf16x8*)&Vth[p][sw8(ni * 16 + lm, ks * 4 + quad)];
                o[ni] = __builtin_amdgcn_mfma_f32_16x16x32_bf16(ph, vh, o[ni], 0, 0, 0);
            }
        }
    }

    // epilogue: one cross-lane row-sum reduction, normalize, store concat hi
    #pragma unroll
    for (int j = 0; j < 4; ++j) {
        float ls = lsum[j];
        ls += __shfl_xor(ls, 1);
        ls += __shfl_xor(ls, 2);
        ls += __shfl_xor(ls, 4);
        ls += __shfl_xor(ls, 8);
        const float inv = 1.0f / ls;
        const int q = qwbase + j;
        #pragma unroll
        for (int ni = 0; ni < 4; ++ni)
            ch[((size_t)b * 2048 + q) * 1024 + h * 64 + ni * 16 + lm] =
                (unsigned short)f2b(o[ni][j] * inv);
    }
}

extern "C" void kernel_launch(void* const* d_in, const int* in_sizes, int n_in,
                              void* d_out, int out_size, void* d_ws, size_t ws_size,
                              hipStream_t stream) {
    const float* x    = (const float*)d_in[0];
    const float* mask = (const float*)d_in[1];
    const float* Wq   = (const float*)d_in[2];
    const float* bq   = (const float*)d_in[3];
    const float* Wk   = (const float*)d_in[4];
    const float* bk   = (const float*)d_in[5];
    const float* Wv   = (const float*)d_in[6];
    const float* bv   = (const float*)d_in[7];
    const float* Wo   = (const float*)d_in[8];
    const float* bo   = (const float*)d_in[9];

    unsigned short* wsS = (unsigned short*)d_ws;

    // 1. pre-split: W -> hi (Wq*QSC); x -> hi
    split_wx<<<8192, 256, 0, stream>>>(Wq, Wk, Wv, Wo, x,
        wsS + OFF_WH, wsS + OFF_XH);

    // 2. Q/K/V projections, ONE 768-block launch, all 1-term
    gemm_qkv<<<dim3(8, 32, 3), 256, 0, stream>>>(wsS, bq, bk, bv);

    // 3. flash attention (64-row, QK 2t / PV 1t, mask reg-dbuf, exp2)
    attn_fast<<<dim3(32, 16, 2), 256, 0, stream>>>(wsS, mask, wsS + OFF_CH);

    // 4. output projection: 512 threads, 8 waves/CU
    gemm_out<<<dim3(8, 32), 512, 0, stream>>>(
        wsS + OFF_CH, wsS, bo, (float*)d_out);
}

// Round 16
// 246.600 us; speedup vs baseline: 1.2059x; 1.2059x over previous
//
#include <hip/hip_runtime.h>
#include <hip/hip_bf16.h>
#include <math.h>

// B=2, N=2048, M=1024, H=16, DK=64. fp32 in/out.
// R16 = R14 attn structure (proven 88us, no scratch) + R15's safe exp2 fold:
// QSC = 0.125*log2(e) pre-folded into Wq/bq -> p = exp2(s*mask) directly.
// R15's mask register double-buffer REVERTED: runtime-indexed mbuf[2][..]
// was demoted to scratch (WRITE_SIZE 8MB->86MB, attn 88->136us).
// Precision plan (absmax 9.77e-4, stable since R7):
//   all projections 1-term | QK 2-term (ql = fp32-accumulator residue) | PV 1t

typedef __attribute__((ext_vector_type(8))) short bf16x8;
typedef __attribute__((ext_vector_type(4))) float f32x4;

typedef __attribute__((address_space(1))) void gvoid;   // global
typedef __attribute__((address_space(3))) void lvoid;   // LDS

#define QSC 0.18033688011112042f   // 0.125 * log2(e): attn scale + exp2 fold

#if defined(__has_builtin)
#if __has_builtin(__builtin_amdgcn_exp2f)
#define EXP2F(x) __builtin_amdgcn_exp2f(x)
#else
#define EXP2F(x) exp2f(x)
#endif
#else
#define EXP2F(x) exp2f(x)
#endif

// async 16B/lane global->LDS copy: 64 lanes -> 1KB at wave-uniform lds base
__device__ __forceinline__ void gll16(const void* g, void* l) {
    __builtin_amdgcn_global_load_lds(
        (gvoid*)(unsigned long long)g,
        (lvoid*)(unsigned int)(unsigned long long)l,   // low 32b = LDS offset
        16, 0, 0);
}

__device__ __forceinline__ short f2b(float f) {
    union { __hip_bfloat16 h; short s; } u;
    u.h = __float2bfloat16(f);   // RNE
    return u.s;
}
__device__ __forceinline__ float b2f(short s) {
    union { short s; __hip_bfloat16 h; } u;
    u.s = s;
    return __bfloat162float(u.h);
}

// XOR-swizzled element offset inside a [rows][64]-bf16 tile (16B blocks).
__device__ __forceinline__ int sw8(int r, int k8) {       // k8 = octet 0..7
    return (r << 6) + ((k8 ^ (r & 7)) << 3);
}
__device__ __forceinline__ int swe(int r, int k) {        // element-level
    return (r << 6) + (((k >> 3) ^ (r & 7)) << 3) + (k & 7);
}

// workspace layout (SHORT offsets). Every plane = 4194304 shorts (8 MB).
#define PLANE   4194304UL
#define OFF_WH  (0UL * PLANE)    // [4][1024][1024] W hi; Wq pre-scaled by QSC
#define OFF_XH  (1UL * PLANE)    // [4096][1024] x hi
#define OFF_QH  (2UL * PLANE)    // [B,H,N,DK]
#define OFF_QL  (3UL * PLANE)
#define OFF_KH  (4UL * PLANE)    // hi only
#define OFF_VTH (5UL * PLANE)    // [B,H,DK,N] hi only
#define OFF_CH  (6UL * PLANE)    // [B,N,M] concat hi only

// ---------------------------------------------------------------------------
// Pre-split: W -> hi (Wq scaled by QSC); x -> hi only.
// ---------------------------------------------------------------------------
__global__ __launch_bounds__(256) void split_wx(
    const float* __restrict__ Wq, const float* __restrict__ Wk,
    const float* __restrict__ Wv, const float* __restrict__ Wo,
    const float* __restrict__ x,
    unsigned short* __restrict__ wh, unsigned short* __restrict__ xh)
{
    const int i = blockIdx.x * 256 + threadIdx.x;   // float4 idx, 2097152 total
    if (i < 1048576) {                               // weights
        const float* src = (i < 262144) ? Wq : (i < 524288) ? Wk
                         : (i < 786432) ? Wv : Wo;
        const float sc = (i < 262144) ? QSC : 1.0f;  // fold scale + log2e
        const int local = i & 262143;
        float4 v = ((const float4*)src)[local];
        short4 h;
        h.x = f2b(v.x * sc); h.y = f2b(v.y * sc);
        h.z = f2b(v.z * sc); h.w = f2b(v.w * sc);
        ((short4*)(wh + (size_t)(i >> 18) * 1048576))[local] = h;
    } else {                                         // x: hi only
        const int local = i - 1048576;
        float4 v = ((const float4*)x)[local];
        short4 h;
        h.x = f2b(v.x); h.y = f2b(v.y); h.z = f2b(v.z); h.w = f2b(v.w);
        ((short4*)xh)[local] = h;
    }
}

// ---------------------------------------------------------------------------
// Unified 1-term QKV GEMM: ONE launch (8,32,3) = 768 blocks, LDS 32KB.
// z=0: Q -> hi/lo planes (lo = fp32-accumulator residue); z=1: K; z=2: V^T.
// ---------------------------------------------------------------------------
__global__ __launch_bounds__(256, 4) void gemm_qkv(
    unsigned short* __restrict__ wsS,
    const float* __restrict__ bq, const float* __restrict__ bk,
    const float* __restrict__ bv)
{
    __shared__ unsigned short Ash[128 * 64];
    __shared__ unsigned short Bsh[128 * 64];

    const int mode = blockIdx.z;                     // 0 Q, 1 K, 2 V
    const unsigned short* Ah = wsS + OFF_XH;
    const unsigned short* Wh = wsS + OFF_WH + (size_t)mode * 1048576;

    const int tid  = threadIdx.x;
    const int lane = tid & 63;
    const int lm   = lane & 15;
    const int quad = lane >> 4;
    const int w    = tid >> 6;
    const int wr   = w >> 1, wc = w & 1;

    const int row0 = blockIdx.y * 128;
    const int col0 = blockIdx.x * 128;

    const int srow = lane >> 3;
    const int soct = (lane & 7) ^ (srow & 7);

    f32x4 acc[4][4] = {};

    for (int k0 = 0; k0 < 1024; k0 += 64) {
        if (k0) __syncthreads();
        #pragma unroll
        for (int i = 0; i < 4; ++i) {
            const int rb = w * 32 + i * 8;           // wave-uniform row base
            gll16(&Ah[(size_t)(row0 + rb + srow) * 1024 + k0 + soct * 8],
                  &Ash[rb * 64]);
            gll16(&Wh[(size_t)(col0 + rb + srow) * 1024 + k0 + soct * 8],
                  &Bsh[rb * 64]);
        }
        __syncthreads();
        #pragma unroll
        for (int ks = 0; ks < 2; ++ks) {
            bf16x8 afh[4], bfh[4];
            #pragma unroll
            for (int mi = 0; mi < 4; ++mi)
                afh[mi] = *(const bf16x8*)&Ash[sw8(wr * 64 + mi * 16 + lm, ks * 4 + quad)];
            #pragma unroll
            for (int ni = 0; ni < 4; ++ni)
                bfh[ni] = *(const bf16x8*)&Bsh[sw8(wc * 64 + ni * 16 + lm, ks * 4 + quad)];
            #pragma unroll
            for (int mi = 0; mi < 4; ++mi) {
                #pragma unroll
                for (int ni = 0; ni < 4; ++ni)
                    acc[mi][ni] = __builtin_amdgcn_mfma_f32_16x16x32_bf16(
                        afh[mi], bfh[ni], acc[mi][ni], 0, 0, 0);
            }
        }
    }

    unsigned short* qh  = wsS + OFF_QH;
    unsigned short* ql  = wsS + OFF_QL;
    unsigned short* kh  = wsS + OFF_KH;
    unsigned short* vth = wsS + OFF_VTH;
    const float* bias = (mode == 0) ? bq : (mode == 1) ? bk : bv;
    const float bscale = (mode == 0) ? QSC : 1.0f;

    #pragma unroll
    for (int ni = 0; ni < 4; ++ni) {
        const int f = col0 + wc * 64 + ni * 16 + lm;
        const float bvv = bias[f] * bscale;
        const int h = f >> 6, d = f & 63;
        #pragma unroll
        for (int mi = 0; mi < 4; ++mi) {
            #pragma unroll
            for (int j = 0; j < 4; ++j) {
                const int row = row0 + wr * 64 + mi * 16 + quad * 4 + j;
                const float val = acc[mi][ni][j] + bvv;
                const int bb = row >> 11, n = row & 2047;
                const short hs = f2b(val);
                if (mode == 0) {
                    const size_t idx = ((size_t)(bb * 16 + h) * 2048 + n) * 64 + d;
                    qh[idx] = hs;
                    ql[idx] = f2b(val - b2f(hs));   // fp32-accumulator residue
                } else if (mode == 1) {
                    kh[((size_t)(bb * 16 + h) * 2048 + n) * 64 + d] = hs;
                } else {
                    vth[((size_t)(bb * 16 + h) * 64 + d) * 2048 + n] = hs;
                }
            }
        }
    }
}

// ---------------------------------------------------------------------------
// 1-term output projection, 512 threads / 8 waves (R14).
// ---------------------------------------------------------------------------
__global__ __launch_bounds__(512, 2) void gemm_out(
    const unsigned short* __restrict__ Ah,
    unsigned short* __restrict__ wsS,
    const float* __restrict__ bias_p, float* __restrict__ oout)
{
    __shared__ unsigned short Ash[128 * 64];
    __shared__ unsigned short Bsh[128 * 64];

    const unsigned short* Wh = wsS + OFF_WH + 3UL * 1048576;

    const int tid  = threadIdx.x;
    const int lane = tid & 63;
    const int lm   = lane & 15;
    const int quad = lane >> 4;
    const int w    = tid >> 6;          // 0..7
    const int wr   = w >> 2;            // 0..1  (64-row half)
    const int wc   = w & 3;             // 0..3  (32-col quarter)

    const int row0 = blockIdx.y * 128;
    const int col0 = blockIdx.x * 128;

    const int srow = lane >> 3;
    const int soct = (lane & 7) ^ (srow & 7);

    f32x4 acc[4][2] = {};

    for (int k0 = 0; k0 < 1024; k0 += 64) {
        if (k0) __syncthreads();
        #pragma unroll
        for (int i = 0; i < 2; ++i) {
            const int rb = w * 16 + i * 8;
            gll16(&Ah[(size_t)(row0 + rb + srow) * 1024 + k0 + soct * 8],
                  &Ash[rb * 64]);
            gll16(&Wh[(size_t)(col0 + rb + srow) * 1024 + k0 + soct * 8],
                  &Bsh[rb * 64]);
        }
        __syncthreads();
        #pragma unroll
        for (int ks = 0; ks < 2; ++ks) {
            bf16x8 afh[4], bfh[2];
            #pragma unroll
            for (int mi = 0; mi < 4; ++mi)
                afh[mi] = *(const bf16x8*)&Ash[sw8(wr * 64 + mi * 16 + lm, ks * 4 + quad)];
            #pragma unroll
            for (int ni = 0; ni < 2; ++ni)
                bfh[ni] = *(const bf16x8*)&Bsh[sw8(wc * 32 + ni * 16 + lm, ks * 4 + quad)];
            #pragma unroll
            for (int mi = 0; mi < 4; ++mi) {
                #pragma unroll
                for (int ni = 0; ni < 2; ++ni)
                    acc[mi][ni] = __builtin_amdgcn_mfma_f32_16x16x32_bf16(
                        afh[mi], bfh[ni], acc[mi][ni], 0, 0, 0);
            }
        }
    }

    #pragma unroll
    for (int ni = 0; ni < 2; ++ni) {
        const int f = col0 + wc * 32 + ni * 16 + lm;
        const float bvv = bias_p[f];
        #pragma unroll
        for (int mi = 0; mi < 4; ++mi) {
            #pragma unroll
            for (int j = 0; j < 4; ++j) {
                const int row = row0 + wr * 64 + mi * 16 + quad * 4 + j;
                oout[(size_t)row * 1024 + f] = acc[mi][ni][j] + bvv;
            }
        }
    }
}

// ---------------------------------------------------------------------------
// Flash attention (R14 structure, proven no-scratch): 64 q-rows/block,
// deferred softmax, async K/V dbuf, one barrier per K-tile, per-iter mask
// loads, p = exp2(s*mask) with QSC pre-folded into q. QK 2t, PV 1t.
// LDS 40KB -> 4 blocks/CU.
// ---------------------------------------------------------------------------
__global__ __launch_bounds__(256, 4) void attn_fast(
    const unsigned short* __restrict__ wsS, const float* __restrict__ mask,
    unsigned short* __restrict__ ch)
{
    __shared__ unsigned short Ksh[2][64 * 64];   // [buf][kcol][d] hi
    __shared__ unsigned short Vth[2][64 * 64];   // [buf][d][k]    hi
    __shared__ unsigned short Psh[4][16 * 64];   // per-wave [q][k] hi

    const int tid  = threadIdx.x;
    const int lane = tid & 63;
    const int lm   = lane & 15;
    const int quad = lane >> 4;
    const int w    = tid >> 6;

    const int q0 = blockIdx.x * 64;
    const int h  = blockIdx.y;
    const int b  = blockIdx.z;
    const int bh = b * 16 + h;

    const unsigned short* Qhg = wsS + OFF_QH  + (size_t)bh * 2048 * 64;
    const unsigned short* Qlg = wsS + OFF_QL  + (size_t)bh * 2048 * 64;
    const unsigned short* Khg = wsS + OFF_KH  + (size_t)bh * 2048 * 64;
    const unsigned short* Vhg = wsS + OFF_VTH + (size_t)bh * 64 * 2048;
    const float* Mg = mask + (size_t)b * 2048 * 2048;

    // Q frags in registers (this wave's 16 q-rows); QSC pre-folded in q
    bf16x8 qfh[2], qfl[2];
    #pragma unroll
    for (int ks = 0; ks < 2; ++ks) {
        const size_t qo = (size_t)(q0 + w * 16 + lm) * 64 + ks * 32 + quad * 8;
        qfh[ks] = *(const bf16x8*)&Qhg[qo];
        qfl[ks] = *(const bf16x8*)&Qlg[qo];
    }

    const int srow = lane >> 3;
    const int soct = (lane & 7) ^ (srow & 7);

    // prologue: async-load tile 0 into buf 0
    #pragma unroll
    for (int i = 0; i < 2; ++i) {
        const int rb = w * 16 + i * 8;               // wave-uniform row base
        gll16(&Khg[(size_t)(rb + srow) * 64 + soct * 8],   &Ksh[0][rb * 64]);
        gll16(&Vhg[(size_t)(rb + srow) * 2048 + soct * 8], &Vth[0][rb * 64]);
    }

    f32x4 o[4] = {};
    float lsum[4] = {0.f, 0.f, 0.f, 0.f};
    const int qwbase = q0 + w * 16 + quad * 4;

    for (int t = 0; t < 32; ++t) {
        const int k0 = t * 64;
        const int p  = t & 1;

        __syncthreads();   // drains vmcnt -> tile t resident in buf p

        // async-issue tile t+1 into buf 1-p (lands before next barrier)
        if (t < 31) {
            #pragma unroll
            for (int i = 0; i < 2; ++i) {
                const int rb = w * 16 + i * 8;
                gll16(&Khg[(size_t)(k0 + 64 + rb + srow) * 64 + soct * 8],
                      &Ksh[1 - p][rb * 64]);
                gll16(&Vhg[(size_t)(rb + srow) * 2048 + k0 + 64 + soct * 8],
                      &Vth[1 - p][rb * 64]);
            }
        }

        float mreg[4][4];
        #pragma unroll
        for (int j = 0; j < 4; ++j)
            #pragma unroll
            for (int ni = 0; ni < 4; ++ni)
                mreg[j][ni] = Mg[(size_t)(qwbase + j) * 2048 + k0 + ni * 16 + lm];

        // S ~= (qh+ql) K_hi^T : 2 MFMA per (ks,ni); QSC+log2e folded in q
        f32x4 s[4] = {};
        #pragma unroll
        for (int ks = 0; ks < 2; ++ks) {
            #pragma unroll
            for (int ni = 0; ni < 4; ++ni) {
                bf16x8 kh = *(const bf16x8*)&Ksh[p][sw8(ni * 16 + lm, ks * 4 + quad)];
                s[ni] = __builtin_amdgcn_mfma_f32_16x16x32_bf16(qfh[ks], kh, s[ni], 0, 0, 0);
                s[ni] = __builtin_amdgcn_mfma_f32_16x16x32_bf16(qfl[ks], kh, s[ni], 0, 0, 0);
            }
        }

        // p = exp2(s * mask); per-lane partial row-sums; P(hi) -> own-wave LDS
        #pragma unroll
        for (int j = 0; j < 4; ++j) {
            #pragma unroll
            for (int ni = 0; ni < 4; ++ni) {
                const float pv = EXP2F(s[ni][j] * mreg[j][ni]);
                lsum[j] += pv;
                Psh[w][swe(quad * 4 + j, ni * 16 + lm)] = f2b(pv);
            }
        }

        // O += P_hi @ V_hi : 1 MFMA per (ks,ni)
        #pragma unroll
        for (int ks = 0; ks < 2; ++ks) {
            bf16x8 ph = *(const bf16x8*)&Psh[w][sw8(lm, ks * 4 + quad)];
            #pragma unroll
            for (int ni = 0; ni < 4; ++ni) {
                bf16x8 vh = *(const bf16x8*)&Vth[p][sw8(ni * 16 + lm, ks * 4 + quad)];
                o[ni] = __builtin_amdgcn_mfma_f32_16x16x32_bf16(ph, vh, o[ni], 0, 0, 0);
            }
        }
    }

    // epilogue: one cross-lane row-sum reduction, normalize, store concat hi
    #pragma unroll
    for (int j = 0; j < 4; ++j) {
        float ls = lsum[j];
        ls += __shfl_xor(ls, 1);
        ls += __shfl_xor(ls, 2);
        ls += __shfl_xor(ls, 4);
        ls += __shfl_xor(ls, 8);
        const float inv = 1.0f / ls;
        const int q = qwbase + j;
        #pragma unroll
        for (int ni = 0; ni < 4; ++ni)
            ch[((size_t)b * 2048 + q) * 1024 + h * 64 + ni * 16 + lm] =
                (unsigned short)f2b(o[ni][j] * inv);
    }
}

extern "C" void kernel_launch(void* const* d_in, const int* in_sizes, int n_in,
                              void* d_out, int out_size, void* d_ws, size_t ws_size,
                              hipStream_t stream) {
    const float* x    = (const float*)d_in[0];
    const float* mask = (const float*)d_in[1];
    const float* Wq   = (const float*)d_in[2];
    const float* bq   = (const float*)d_in[3];
    const float* Wk   = (const float*)d_in[4];
    const float* bk   = (const float*)d_in[5];
    const float* Wv   = (const float*)d_in[6];
    const float* bv   = (const float*)d_in[7];
    const float* Wo   = (const float*)d_in[8];
    const float* bo   = (const float*)d_in[9];

    unsigned short* wsS = (unsigned short*)d_ws;

    // 1. pre-split: W -> hi (Wq*QSC); x -> hi
    split_wx<<<8192, 256, 0, stream>>>(Wq, Wk, Wv, Wo, x,
        wsS + OFF_WH, wsS + OFF_XH);

    // 2. Q/K/V projections, ONE 768-block launch, all 1-term
    gemm_qkv<<<dim3(8, 32, 3), 256, 0, stream>>>(wsS, bq, bk, bv);

    // 3. flash attention (64-row, QK 2t / PV 1t, exp2 fold)
    attn_fast<<<dim3(32, 16, 2), 256, 0, stream>>>(wsS, mask, wsS + OFF_CH);

    // 4. output projection: 512 threads, 8 waves/CU
    gemm_out<<<dim3(8, 32), 512, 0, stream>>>(
        wsS + OFF_CH, wsS, bo, (float*)d_out);
}